// Round 2
// baseline (1087.650 us; speedup 1.0000x reference)
//
#include <hip/hip_runtime.h>
#include <hip/hip_bf16.h>
#include <math.h>

typedef unsigned short u16;
typedef short s16x8 __attribute__((ext_vector_type(8)));
typedef float f32x4 __attribute__((ext_vector_type(4)));
typedef unsigned short u16x4 __attribute__((ext_vector_type(4)));

// Problem constants
#define NLAYER 4
#define BB 4
#define TT 2048
#define DD 1024
#define HH 1024
#define FF 256
#define MM 8192          // B*T
#define CL 64            // scan chunk length
#define NC 32            // chunks = T/CL
#define PLANE 4096       // L*H (param plane stride)
#define STPLANE 131072   // B*NC*H (scan-state plane stride)

__device__ __forceinline__ u16 f2bf(float f) {
  __hip_bfloat16 h = __float2bfloat16(f);
  return __builtin_bit_cast(u16, h);
}
__device__ __forceinline__ float bf2f(u16 u) {
  __hip_bfloat16 h = __builtin_bit_cast(__hip_bfloat16, u);
  return __bfloat162float(h);
}

// ---------------- params: lam, gamma, lam^CL ----------------
__global__ __launch_bounds__(256) void params_kernel(
    const float* __restrict__ nu_log, const float* __restrict__ theta_log,
    float* __restrict__ P) {
  int i = blockIdx.x * 256 + threadIdx.x;
  if (i >= PLANE) return;
  float nu = expf(nu_log[i]);
  float th = expf(theta_log[i]);
  float r = expf(-nu);
  P[i]           = r * cosf(th);                       // lam_re
  P[PLANE + i]   = r * sinf(th);                       // lam_im
  P[2*PLANE + i] = sqrtf(1.f - expf(-2.f * nu) + 1e-5f); // gamma
  float rC = expf(-(float)CL * nu);
  float thC = (float)CL * th;
  P[3*PLANE + i] = rC * cosf(thC);                     // lamC_re
  P[4*PLANE + i] = rC * sinf(thC);                     // lamC_im
}

// ---------------- generic fp32 -> bf16 ----------------
__global__ __launch_bounds__(256) void f2bf_kernel(
    const float* __restrict__ src, u16* __restrict__ dst, int n) {
  int i = blockIdx.x * 256 + threadIdx.x;
  if (i < n) dst[i] = f2bf(src[i]);
}

// ---------------- per-layer weight conversion ----------------
__global__ __launch_bounds__(256) void conv_layer_kernel(
    const float* __restrict__ Bre, const float* __restrict__ Bim,
    const float* __restrict__ Cre, const float* __restrict__ Cim,
    const float* __restrict__ w1, const float* __restrict__ w2,
    const float* __restrict__ gamma,
    u16* __restrict__ wBn, u16* __restrict__ wC,
    u16* __restrict__ w1b, u16* __restrict__ w2b) {
  int idx = blockIdx.x * 256 + threadIdx.x;
  if (idx < 2097152) {
    int n = idx >> 10, d = idx & 1023;
    float v = (n < 1024) ? Bre[n * 1024 + d] * gamma[n]
                         : Bim[(n - 1024) * 1024 + d] * gamma[n - 1024];
    wBn[idx] = f2bf(v);
  } else if (idx < 4194304) {
    int i = idx - 2097152;
    int d = i >> 11, k = i & 2047;
    float v = (k < 1024) ? Cre[d * 1024 + k] : -Cim[d * 1024 + (k - 1024)];
    wC[i] = f2bf(v);
  } else if (idx < 5242880) {
    int i = idx - 4194304;
    w1b[i] = f2bf(w1[i]);
  } else if (idx < 6291456) {
    int i = idx - 5242880;
    w2b[i] = f2bf(w2[i]);
  }
}

// ---------------- LayerNorm: x fp32 [8192,1024] -> xn bf16 ----------------
__global__ __launch_bounds__(256) void ln_kernel(
    const float* __restrict__ x, const float* __restrict__ sc,
    const float* __restrict__ bi, u16* __restrict__ xn) {
  const int row = blockIdx.x;
  const int tid = threadIdx.x;
  const float4 v = ((const float4*)(x + (size_t)row * 1024))[tid];
  float s = v.x + v.y + v.z + v.w;
  float ss = v.x * v.x + v.y * v.y + v.z * v.z + v.w * v.w;
  __shared__ float r1[256], r2[256];
  r1[tid] = s; r2[tid] = ss;
  __syncthreads();
  for (int stp = 128; stp > 0; stp >>= 1) {
    if (tid < stp) { r1[tid] += r1[tid + stp]; r2[tid] += r2[tid + stp]; }
    __syncthreads();
  }
  const float mu = r1[0] * 0.0009765625f;
  const float var = r2[0] * 0.0009765625f - mu * mu;
  const float inv = rsqrtf(var + 1e-5f);
  const int c = tid * 4;
  u16x4 o;
  o.x = f2bf((v.x - mu) * inv * sc[c]     + bi[c]);
  o.y = f2bf((v.y - mu) * inv * sc[c + 1] + bi[c + 1]);
  o.z = f2bf((v.z - mu) * inv * sc[c + 2] + bi[c + 2]);
  o.w = f2bf((v.w - mu) * inv * sc[c + 3] + bi[c + 3]);
  *(u16x4*)&xn[(size_t)row * 1024 + c] = o;
}

// ---------------- scan phase A: local chunk scans (in-place on Bu) ----------
__global__ __launch_bounds__(256) void scanA_kernel(
    u16* __restrict__ Bu, const float* __restrict__ P, float* __restrict__ st,
    int l) {
  const int tid = blockIdx.x * 256 + threadIdx.x;   // 65536
  const int h2 = tid & 511;
  const int c = (tid >> 9) & 31;
  const int b = tid >> 14;
  const int h = h2 * 2;
  const float lr0 = P[l * 1024 + h],     li0 = P[PLANE + l * 1024 + h];
  const float lr1 = P[l * 1024 + h + 1], li1 = P[PLANE + l * 1024 + h + 1];
  const size_t base = ((size_t)(b * TT + c * CL)) * 2048 + h;
  float h0r = 0.f, h0i = 0.f, h1r = 0.f, h1i = 0.f;
  for (int j = 0; j < CL; j++) {
    size_t o = base + (size_t)j * 2048;
    uint re2 = *(const uint*)(Bu + o);
    uint im2 = *(const uint*)(Bu + o + 1024);
    float b0r = bf2f((u16)(re2 & 0xffffu)), b1r = bf2f((u16)(re2 >> 16));
    float b0i = bf2f((u16)(im2 & 0xffffu)), b1i = bf2f((u16)(im2 >> 16));
    float t0r = lr0 * h0r - li0 * h0i + b0r;
    float t0i = lr0 * h0i + li0 * h0r + b0i;
    float t1r = lr1 * h1r - li1 * h1i + b1r;
    float t1i = lr1 * h1i + li1 * h1r + b1i;
    h0r = t0r; h0i = t0i; h1r = t1r; h1i = t1i;
    *(uint*)(Bu + o)        = (uint)f2bf(h0r) | ((uint)f2bf(h1r) << 16);
    *(uint*)(Bu + o + 1024) = (uint)f2bf(h0i) | ((uint)f2bf(h1i) << 16);
  }
  size_t si = ((size_t)(b * NC + c)) * 1024 + h;
  st[si] = h0r; st[si + 1] = h1r;
  st[STPLANE + si] = h0i; st[STPLANE + si + 1] = h1i;
}

// ---------------- scan phase B: chunk-prefix (in-place: st[c] := prefix) ----
__global__ __launch_bounds__(256) void scanB_kernel(
    float* __restrict__ st, const float* __restrict__ P, int l) {
  const int tid = blockIdx.x * 256 + threadIdx.x;   // 4096
  const int h = tid & 1023;
  const int b = tid >> 10;
  const float cr = P[3*PLANE + l * 1024 + h], ci = P[4*PLANE + l * 1024 + h];
  float pr = 0.f, pi = 0.f;
  for (int c = 0; c < NC; c++) {
    size_t i = ((size_t)(b * NC + c)) * 1024 + h;
    float sr = st[i], sim = st[STPLANE + i];
    st[i] = pr; st[STPLANE + i] = pi;
    float nr = cr * pr - ci * pi + sr;
    float ni = cr * pi + ci * pr + sim;
    pr = nr; pi = ni;
  }
}

// ---------------- scan phase C: add lam^{j+1} * prefix ----------------
__global__ __launch_bounds__(256) void scanC_kernel(
    u16* __restrict__ Bu, const float* __restrict__ P,
    const float* __restrict__ st, int l) {
  const int tid = blockIdx.x * 256 + threadIdx.x;   // 65536
  const int h2 = tid & 511;
  const int c = (tid >> 9) & 31;
  const int b = tid >> 14;
  if (c == 0) return;  // prefix is exactly zero
  const int h = h2 * 2;
  const float lr0 = P[l * 1024 + h],     li0 = P[PLANE + l * 1024 + h];
  const float lr1 = P[l * 1024 + h + 1], li1 = P[PLANE + l * 1024 + h + 1];
  size_t si = ((size_t)(b * NC + c)) * 1024 + h;
  float q0r = st[si], q1r = st[si + 1];
  float q0i = st[STPLANE + si], q1i = st[STPLANE + si + 1];
  const size_t base = ((size_t)(b * TT + c * CL)) * 2048 + h;
  for (int j = 0; j < CL; j++) {
    float t0r = lr0 * q0r - li0 * q0i;
    float t0i = lr0 * q0i + li0 * q0r;
    float t1r = lr1 * q1r - li1 * q1i;
    float t1i = lr1 * q1i + li1 * q1r;
    q0r = t0r; q0i = t0i; q1r = t1r; q1i = t1i;
    size_t o = base + (size_t)j * 2048;
    uint re2 = *(const uint*)(Bu + o);
    uint im2 = *(const uint*)(Bu + o + 1024);
    float v0r = bf2f((u16)(re2 & 0xffffu)) + q0r;
    float v1r = bf2f((u16)(re2 >> 16))     + q1r;
    float v0i = bf2f((u16)(im2 & 0xffffu)) + q0i;
    float v1i = bf2f((u16)(im2 >> 16))     + q1i;
    *(uint*)(Bu + o)        = (uint)f2bf(v0r) | ((uint)f2bf(v1r) << 16);
    *(uint*)(Bu + o + 1024) = (uint)f2bf(v0i) | ((uint)f2bf(v1i) << 16);
  }
}

// ---- async staging: 32 rows x 64 cols bf16 per wave via global_load_lds ----
// LDS dest is wave-uniform base + lane*16B (no padding possible). Lane's 16B
// lands at row (lane>>3), col8 (lane&7)*8 relative to the uniform base --
// global per-lane address must match exactly.
__device__ __forceinline__ void stage32(const u16* __restrict__ gbase,
                                        int row_stride, u16* lds_base,
                                        int wave, int lane) {
  const int r8 = lane >> 3;
  const int c8 = (lane & 7) * 8;
  #pragma unroll
  for (int i = 0; i < 4; i++) {
    const int rbase = wave * 32 + i * 8;
    const u16* g = gbase + (size_t)(rbase + r8) * row_stride + c8;
    u16* l = lds_base + rbase * 64;
    __builtin_amdgcn_global_load_lds(
        (const __attribute__((address_space(1))) void*)g,
        (__attribute__((address_space(3))) void*)l, 16, 0, 0);
  }
}

// ---------------- MFMA GEMM: C[M,N] = A[M,K] * W[N,K]^T ----------------
// MODE 0: store bf16 | 1: fp32+bias | 2: +xn*ddiag, GELU, bf16 | 3: GLU += x
template <int MODE>
__global__ __launch_bounds__(256, 2) void gemm_kernel(
    const u16* __restrict__ A, const u16* __restrict__ W,
    const u16* __restrict__ W2, int K, int N, void* __restrict__ outp,
    const float* __restrict__ bias, const float* __restrict__ bias2,
    const float* __restrict__ ddiag, const u16* __restrict__ xnp) {
  __shared__ u16 As[128 * 64];
  __shared__ u16 Bs[128 * 64];
  __shared__ u16 Bs2[(MODE == 3) ? 128 * 64 : 64];

  const int tid = threadIdx.x;
  const int m0 = blockIdx.x * 128;
  const int n0 = blockIdx.y * 128;
  const int wave = tid >> 6;
  const int lane = tid & 63;
  const int wm = wave & 1;
  const int wn = wave >> 1;
  const int lr = lane & 15;
  const int quad = lane >> 4;

  f32x4 acc[4][4];
  f32x4 acc2[4][4];
  #pragma unroll
  for (int i = 0; i < 4; i++)
    #pragma unroll
    for (int j = 0; j < 4; j++)
      #pragma unroll
      for (int r = 0; r < 4; r++) {
        acc[i][j][r] = 0.f;
        if constexpr (MODE == 3) acc2[i][j][r] = 0.f;
      }

  for (int kb = 0; kb < K; kb += 64) {
    stage32(A + (size_t)m0 * K + kb, K, As, wave, lane);
    stage32(W + (size_t)n0 * K + kb, K, Bs, wave, lane);
    if constexpr (MODE == 3)
      stage32(W2 + (size_t)n0 * K + kb, K, Bs2, wave, lane);
    __syncthreads();   // compiler emits vmcnt(0) drain -> LDS data visible
    #pragma unroll
    for (int ks = 0; ks < 2; ks++) {
      s16x8 af[4], bfr[4], bfr2[4];
      #pragma unroll
      for (int t = 0; t < 4; t++) {
        af[t]  = *(const s16x8*)&As[(wm * 64 + t * 16 + lr) * 64 + ks * 32 + quad * 8];
        bfr[t] = *(const s16x8*)&Bs[(wn * 64 + t * 16 + lr) * 64 + ks * 32 + quad * 8];
        if constexpr (MODE == 3)
          bfr2[t] = *(const s16x8*)&Bs2[(wn * 64 + t * 16 + lr) * 64 + ks * 32 + quad * 8];
      }
      #pragma unroll
      for (int mt = 0; mt < 4; mt++)
        #pragma unroll
        for (int nt = 0; nt < 4; nt++) {
          acc[mt][nt] = __builtin_amdgcn_mfma_f32_16x16x32_bf16(
              af[mt], bfr[nt], acc[mt][nt], 0, 0, 0);
          if constexpr (MODE == 3)
            acc2[mt][nt] = __builtin_amdgcn_mfma_f32_16x16x32_bf16(
                af[mt], bfr2[nt], acc2[mt][nt], 0, 0, 0);
        }
    }
    __syncthreads();
  }

  // Epilogue. C/D layout: row = quad*4 + r (m), col = lane&15 (n).
  const int mbase = m0 + wm * 64 + quad * 4;
  const int nbase = n0 + wn * 64 + lr;
  #pragma unroll
  for (int mt = 0; mt < 4; mt++)
    #pragma unroll
    for (int nt = 0; nt < 4; nt++) {
      const int n = nbase + nt * 16;
      #pragma unroll
      for (int r = 0; r < 4; r++) {
        const int m = mbase + mt * 16 + r;
        const float v = acc[mt][nt][r];
        if constexpr (MODE == 0) {
          ((u16*)outp)[(size_t)m * N + n] = f2bf(v);
        } else if constexpr (MODE == 1) {
          ((float*)outp)[(size_t)m * N + n] = v + bias[n];
        } else if constexpr (MODE == 2) {
          float t = v + bf2f(xnp[(size_t)m * 1024 + n]) * ddiag[n];
          float g = t * 0.5f * (1.f + erff(t * 0.70710678118f));
          ((u16*)outp)[(size_t)m * N + n] = f2bf(g);
        } else {
          float a = v + bias[n];
          float g2 = acc2[mt][nt][r] + bias2[n];
          float sig = 1.f / (1.f + expf(-g2));
          float* xp = (float*)outp;
          xp[(size_t)m * N + n] += a * sig;
        }
      }
    }
}

extern "C" void kernel_launch(void* const* d_in, const int* in_sizes, int n_in,
                              void* d_out, int out_size, void* d_ws,
                              size_t ws_size, hipStream_t stream) {
  const float* inputs    = (const float*)d_in[0];
  const float* W_in      = (const float*)d_in[1];
  const float* b_in      = (const float*)d_in[2];
  const float* nu_log    = (const float*)d_in[3];
  const float* theta_log = (const float*)d_in[4];
  const float* B_re      = (const float*)d_in[5];
  const float* B_im      = (const float*)d_in[6];
  const float* C_re      = (const float*)d_in[7];
  const float* C_im      = (const float*)d_in[8];
  const float* D_diag    = (const float*)d_in[9];
  const float* ln_s      = (const float*)d_in[10];
  const float* ln_b      = (const float*)d_in[11];
  const float* w1        = (const float*)d_in[12];
  const float* b1        = (const float*)d_in[13];
  const float* w2        = (const float*)d_in[14];
  const float* b2        = (const float*)d_in[15];
  float* x = (float*)d_out;

  char* p = (char*)d_ws;
  auto alloc = [&](size_t bytes) -> char* {
    char* r = p;
    p += (bytes + 255) & ~(size_t)255;
    return r;
  };
  float* P       = (float*)alloc(5 * PLANE * 4);
  u16* inputs_bf = (u16*)alloc((size_t)MM * FF * 2);
  u16* Win_bf    = (u16*)alloc((size_t)DD * FF * 2);
  u16* xn        = (u16*)alloc((size_t)MM * DD * 2);
  u16* Bu        = (u16*)alloc((size_t)MM * 2048 * 2);
  u16* yg        = (u16*)alloc((size_t)MM * DD * 2);
  float* st      = (float*)alloc(2 * (size_t)STPLANE * 4);
  u16* wBn       = (u16*)alloc((size_t)2048 * 1024 * 2);
  u16* wC        = (u16*)alloc((size_t)1024 * 2048 * 2);
  u16* w1b       = (u16*)alloc((size_t)1024 * 1024 * 2);
  u16* w2b       = (u16*)alloc((size_t)1024 * 1024 * 2);

  params_kernel<<<16, 256, 0, stream>>>(nu_log, theta_log, P);
  f2bf_kernel<<<(MM * FF + 255) / 256, 256, 0, stream>>>(inputs, inputs_bf, MM * FF);
  f2bf_kernel<<<(DD * FF + 255) / 256, 256, 0, stream>>>(W_in, Win_bf, DD * FF);

  // x = inputs @ W_in^T + b_in
  gemm_kernel<1><<<dim3(64, 8), 256, 0, stream>>>(
      inputs_bf, Win_bf, nullptr, FF, DD, x, b_in, nullptr, nullptr, nullptr);

  for (int l = 0; l < NLAYER; l++) {
    ln_kernel<<<MM, 256, 0, stream>>>(x, ln_s + l * 1024, ln_b + l * 1024, xn);
    conv_layer_kernel<<<24576, 256, 0, stream>>>(
        B_re + (size_t)l * 1048576, B_im + (size_t)l * 1048576,
        C_re + (size_t)l * 1048576, C_im + (size_t)l * 1048576,
        w1 + (size_t)l * 1048576, w2 + (size_t)l * 1048576,
        P + 2 * PLANE + l * 1024, wBn, wC, w1b, w2b);
    // Bu = xn @ [gamma*B_re ; gamma*B_im]^T   (N = 2048)
    gemm_kernel<0><<<dim3(64, 16), 256, 0, stream>>>(
        xn, wBn, nullptr, DD, 2048, Bu, nullptr, nullptr, nullptr, nullptr);
    scanA_kernel<<<256, 256, 0, stream>>>(Bu, P, st, l);
    scanB_kernel<<<16, 256, 0, stream>>>(st, P, l);
    scanC_kernel<<<256, 256, 0, stream>>>(Bu, P, st, l);
    // yg = gelu( [hs_re|hs_im] @ [C_re ; -C_im]^T + xn*D_diag )   (K = 2048)
    gemm_kernel<2><<<dim3(64, 8), 256, 0, stream>>>(
        Bu, wC, nullptr, 2048, DD, yg, nullptr, nullptr, D_diag + l * 1024, xn);
    // x += (yg@w1^T + b1) * sigmoid(yg@w2^T + b2)
    gemm_kernel<3><<<dim3(64, 8), 256, 0, stream>>>(
        yg, w1b, w2b, DD, DD, x, b1 + l * 1024, b2 + l * 1024, nullptr, nullptr);
  }
}

// Round 3
// 954.468 us; speedup vs baseline: 1.1395x; 1.1395x over previous
//
#include <hip/hip_runtime.h>
#include <hip/hip_bf16.h>
#include <math.h>

typedef unsigned short u16;
typedef short s16x8 __attribute__((ext_vector_type(8)));
typedef float f32x4 __attribute__((ext_vector_type(4)));
typedef unsigned short u16x4 __attribute__((ext_vector_type(4)));

// Problem constants
#define NLAYER 4
#define BB 4
#define TT 2048
#define DD 1024
#define HH 1024
#define FF 256
#define MM 8192          // B*T
#define CL 64            // scan chunk length
#define NC 32            // chunks = T/CL
#define PLANE 4096       // L*H (param plane stride)
#define STPLANE 131072   // B*NC*H (scan-state plane stride)

__device__ __forceinline__ u16 f2bf(float f) {
  __hip_bfloat16 h = __float2bfloat16(f);
  return __builtin_bit_cast(u16, h);
}
__device__ __forceinline__ float bf2f(u16 u) {
  __hip_bfloat16 h = __builtin_bit_cast(__hip_bfloat16, u);
  return __bfloat162float(h);
}

// ---------------- params: lam, gamma, lam^CL ----------------
__global__ __launch_bounds__(256) void params_kernel(
    const float* __restrict__ nu_log, const float* __restrict__ theta_log,
    float* __restrict__ P) {
  int i = blockIdx.x * 256 + threadIdx.x;
  if (i >= PLANE) return;
  float nu = expf(nu_log[i]);
  float th = expf(theta_log[i]);
  float r = expf(-nu);
  P[i]           = r * cosf(th);                       // lam_re
  P[PLANE + i]   = r * sinf(th);                       // lam_im
  P[2*PLANE + i] = sqrtf(1.f - expf(-2.f * nu) + 1e-5f); // gamma
  float rC = expf(-(float)CL * nu);
  float thC = (float)CL * th;
  P[3*PLANE + i] = rC * cosf(thC);                     // lamC_re
  P[4*PLANE + i] = rC * sinf(thC);                     // lamC_im
}

// ---------------- generic fp32 -> bf16 ----------------
__global__ __launch_bounds__(256) void f2bf_kernel(
    const float* __restrict__ src, u16* __restrict__ dst, int n) {
  int i = blockIdx.x * 256 + threadIdx.x;
  if (i < n) dst[i] = f2bf(src[i]);
}

// ---------------- per-layer weight conversion ----------------
__global__ __launch_bounds__(256) void conv_layer_kernel(
    const float* __restrict__ Bre, const float* __restrict__ Bim,
    const float* __restrict__ Cre, const float* __restrict__ Cim,
    const float* __restrict__ w1, const float* __restrict__ w2,
    const float* __restrict__ gamma,
    u16* __restrict__ wBn, u16* __restrict__ wC,
    u16* __restrict__ w1b, u16* __restrict__ w2b) {
  int idx = blockIdx.x * 256 + threadIdx.x;
  if (idx < 2097152) {
    int n = idx >> 10, d = idx & 1023;
    float v = (n < 1024) ? Bre[n * 1024 + d] * gamma[n]
                         : Bim[(n - 1024) * 1024 + d] * gamma[n - 1024];
    wBn[idx] = f2bf(v);
  } else if (idx < 4194304) {
    int i = idx - 2097152;
    int d = i >> 11, k = i & 2047;
    float v = (k < 1024) ? Cre[d * 1024 + k] : -Cim[d * 1024 + (k - 1024)];
    wC[i] = f2bf(v);
  } else if (idx < 5242880) {
    int i = idx - 4194304;
    w1b[i] = f2bf(w1[i]);
  } else if (idx < 6291456) {
    int i = idx - 5242880;
    w2b[i] = f2bf(w2[i]);
  }
}

// ---------------- LayerNorm: x fp32 [8192,1024] -> xn bf16 ----------------
__global__ __launch_bounds__(256) void ln_kernel(
    const float* __restrict__ x, const float* __restrict__ sc,
    const float* __restrict__ bi, u16* __restrict__ xn) {
  const int row = blockIdx.x;
  const int tid = threadIdx.x;
  const float4 v = ((const float4*)(x + (size_t)row * 1024))[tid];
  float s = v.x + v.y + v.z + v.w;
  float ss = v.x * v.x + v.y * v.y + v.z * v.z + v.w * v.w;
  __shared__ float r1[256], r2[256];
  r1[tid] = s; r2[tid] = ss;
  __syncthreads();
  for (int stp = 128; stp > 0; stp >>= 1) {
    if (tid < stp) { r1[tid] += r1[tid + stp]; r2[tid] += r2[tid + stp]; }
    __syncthreads();
  }
  const float mu = r1[0] * 0.0009765625f;
  const float var = r2[0] * 0.0009765625f - mu * mu;
  const float inv = rsqrtf(var + 1e-5f);
  const int c = tid * 4;
  u16x4 o;
  o.x = f2bf((v.x - mu) * inv * sc[c]     + bi[c]);
  o.y = f2bf((v.y - mu) * inv * sc[c + 1] + bi[c + 1]);
  o.z = f2bf((v.z - mu) * inv * sc[c + 2] + bi[c + 2]);
  o.w = f2bf((v.w - mu) * inv * sc[c + 3] + bi[c + 3]);
  *(u16x4*)&xn[(size_t)row * 1024 + c] = o;
}

// ---------------- scan phase A: local chunk scans (in-place on Bu) ----------
__global__ __launch_bounds__(256) void scanA_kernel(
    u16* __restrict__ Bu, const float* __restrict__ P, float* __restrict__ st,
    int l) {
  const int tid = blockIdx.x * 256 + threadIdx.x;   // 65536
  const int h2 = tid & 511;
  const int c = (tid >> 9) & 31;
  const int b = tid >> 14;
  const int h = h2 * 2;
  const float lr0 = P[l * 1024 + h],     li0 = P[PLANE + l * 1024 + h];
  const float lr1 = P[l * 1024 + h + 1], li1 = P[PLANE + l * 1024 + h + 1];
  const size_t base = ((size_t)(b * TT + c * CL)) * 2048 + h;
  float h0r = 0.f, h0i = 0.f, h1r = 0.f, h1i = 0.f;
  for (int j = 0; j < CL; j++) {
    size_t o = base + (size_t)j * 2048;
    uint re2 = *(const uint*)(Bu + o);
    uint im2 = *(const uint*)(Bu + o + 1024);
    float b0r = bf2f((u16)(re2 & 0xffffu)), b1r = bf2f((u16)(re2 >> 16));
    float b0i = bf2f((u16)(im2 & 0xffffu)), b1i = bf2f((u16)(im2 >> 16));
    float t0r = lr0 * h0r - li0 * h0i + b0r;
    float t0i = lr0 * h0i + li0 * h0r + b0i;
    float t1r = lr1 * h1r - li1 * h1i + b1r;
    float t1i = lr1 * h1i + li1 * h1r + b1i;
    h0r = t0r; h0i = t0i; h1r = t1r; h1i = t1i;
    *(uint*)(Bu + o)        = (uint)f2bf(h0r) | ((uint)f2bf(h1r) << 16);
    *(uint*)(Bu + o + 1024) = (uint)f2bf(h0i) | ((uint)f2bf(h1i) << 16);
  }
  size_t si = ((size_t)(b * NC + c)) * 1024 + h;
  st[si] = h0r; st[si + 1] = h1r;
  st[STPLANE + si] = h0i; st[STPLANE + si + 1] = h1i;
}

// ---------------- scan phase B: chunk-prefix (in-place: st[c] := prefix) ----
__global__ __launch_bounds__(256) void scanB_kernel(
    float* __restrict__ st, const float* __restrict__ P, int l) {
  const int tid = blockIdx.x * 256 + threadIdx.x;   // 4096
  const int h = tid & 1023;
  const int b = tid >> 10;
  const float cr = P[3*PLANE + l * 1024 + h], ci = P[4*PLANE + l * 1024 + h];
  float pr = 0.f, pi = 0.f;
  for (int c = 0; c < NC; c++) {
    size_t i = ((size_t)(b * NC + c)) * 1024 + h;
    float sr = st[i], sim = st[STPLANE + i];
    st[i] = pr; st[STPLANE + i] = pi;
    float nr = cr * pr - ci * pi + sr;
    float ni = cr * pi + ci * pr + sim;
    pr = nr; pi = ni;
  }
}

// ---------------- scan phase C: add lam^{j+1} * prefix ----------------
__global__ __launch_bounds__(256) void scanC_kernel(
    u16* __restrict__ Bu, const float* __restrict__ P,
    const float* __restrict__ st, int l) {
  const int tid = blockIdx.x * 256 + threadIdx.x;   // 65536
  const int h2 = tid & 511;
  const int c = (tid >> 9) & 31;
  const int b = tid >> 14;
  if (c == 0) return;  // prefix is exactly zero
  const int h = h2 * 2;
  const float lr0 = P[l * 1024 + h],     li0 = P[PLANE + l * 1024 + h];
  const float lr1 = P[l * 1024 + h + 1], li1 = P[PLANE + l * 1024 + h + 1];
  size_t si = ((size_t)(b * NC + c)) * 1024 + h;
  float q0r = st[si], q1r = st[si + 1];
  float q0i = st[STPLANE + si], q1i = st[STPLANE + si + 1];
  const size_t base = ((size_t)(b * TT + c * CL)) * 2048 + h;
  for (int j = 0; j < CL; j++) {
    float t0r = lr0 * q0r - li0 * q0i;
    float t0i = lr0 * q0i + li0 * q0r;
    float t1r = lr1 * q1r - li1 * q1i;
    float t1i = lr1 * q1i + li1 * q1r;
    q0r = t0r; q0i = t0i; q1r = t1r; q1i = t1i;
    size_t o = base + (size_t)j * 2048;
    uint re2 = *(const uint*)(Bu + o);
    uint im2 = *(const uint*)(Bu + o + 1024);
    float v0r = bf2f((u16)(re2 & 0xffffu)) + q0r;
    float v1r = bf2f((u16)(re2 >> 16))     + q1r;
    float v0i = bf2f((u16)(im2 & 0xffffu)) + q0i;
    float v1i = bf2f((u16)(im2 >> 16))     + q1i;
    *(uint*)(Bu + o)        = (uint)f2bf(v0r) | ((uint)f2bf(v1r) << 16);
    *(uint*)(Bu + o + 1024) = (uint)f2bf(v0i) | ((uint)f2bf(v1i) << 16);
  }
}

// ---- async staging with XOR swizzle --------------------------------------
// LDS row = 64 halves (8 chunks of 16B). Chunk c of row r is stored at slot
// c ^ (r&7): DMA lands lane's 16B at base+lane*16 (slot lane&7, row lane>>3),
// so the lane fetches GLOBAL chunk (lane&7)^(lane>>3 & 7). On the read side
// the fragment slot (ks*4+quad) ^ (lr&7) gives banks ((c^lr)&7)*4 -> distinct
// across lanes 0..7 => 2-way aliasing only (free per m136).
__device__ __forceinline__ void stage_rows(const u16* __restrict__ gbase,
                                           int row_stride, u16* lds_base,
                                           int rows_per_wave, int wave,
                                           int lane) {
  const int r8 = lane >> 3;            // 0..7
  const int slot = lane & 7;
  const int gc = (slot ^ r8) * 8;      // swizzled source chunk (halves)
  #pragma unroll
  for (int i = 0; i < rows_per_wave / 8; i++) {
    const int rbase = wave * rows_per_wave + i * 8;
    const u16* g = gbase + (size_t)(rbase + r8) * row_stride + gc;
    u16* l = lds_base + rbase * 64;
    __builtin_amdgcn_global_load_lds(
        (const __attribute__((address_space(1))) void*)g,
        (__attribute__((address_space(3))) void*)l, 16, 0, 0);
  }
}

// ---------------- MFMA GEMM: C[M,N] = A[M,K] * W[N,K]^T ----------------
// Tile 128x64, BK=64, 4 waves (wm 2 x wn 2), each wave 64x32.
// MODE 0: store bf16 | 1: fp32+bias | 2: +xn*ddiag, GELU, bf16 | 3: GLU += x
template <int MODE>
__global__ __launch_bounds__(256, 4) void gemm_kernel(
    const u16* __restrict__ A, const u16* __restrict__ W,
    const u16* __restrict__ W2, int K, int N, void* __restrict__ outp,
    const float* __restrict__ bias, const float* __restrict__ bias2,
    const float* __restrict__ ddiag, const u16* __restrict__ xnp) {
  __shared__ u16 As[128 * 64];
  __shared__ u16 Bs[64 * 64];
  __shared__ u16 Bs2[(MODE == 3) ? 64 * 64 : 64];

  const int tid = threadIdx.x;
  const int m0 = blockIdx.x * 128;
  const int n0 = blockIdx.y * 64;
  const int wave = tid >> 6;
  const int lane = tid & 63;
  const int wm = wave & 1;
  const int wn = wave >> 1;
  const int lr = lane & 15;
  const int quad = lane >> 4;
  const int sw = lr & 7;               // read-side swizzle key

  f32x4 acc[4][2];
  f32x4 acc2[4][2];
  #pragma unroll
  for (int i = 0; i < 4; i++)
    #pragma unroll
    for (int j = 0; j < 2; j++)
      #pragma unroll
      for (int r = 0; r < 4; r++) {
        acc[i][j][r] = 0.f;
        if constexpr (MODE == 3) acc2[i][j][r] = 0.f;
      }

  for (int kb = 0; kb < K; kb += 64) {
    stage_rows(A + (size_t)m0 * K + kb, K, As, 32, wave, lane);
    stage_rows(W + (size_t)n0 * K + kb, K, Bs, 16, wave, lane);
    if constexpr (MODE == 3)
      stage_rows(W2 + (size_t)n0 * K + kb, K, Bs2, 16, wave, lane);
    __syncthreads();
    #pragma unroll
    for (int ks = 0; ks < 2; ks++) {
      const int cslot = ((ks * 4 + quad) ^ sw) * 8;
      s16x8 af[4], bfr[2], bfr2[2];
      #pragma unroll
      for (int t = 0; t < 4; t++)
        af[t] = *(const s16x8*)&As[(wm * 64 + t * 16 + lr) * 64 + cslot];
      #pragma unroll
      for (int t = 0; t < 2; t++) {
        bfr[t] = *(const s16x8*)&Bs[(wn * 32 + t * 16 + lr) * 64 + cslot];
        if constexpr (MODE == 3)
          bfr2[t] = *(const s16x8*)&Bs2[(wn * 32 + t * 16 + lr) * 64 + cslot];
      }
      #pragma unroll
      for (int mt = 0; mt < 4; mt++)
        #pragma unroll
        for (int nt = 0; nt < 2; nt++) {
          acc[mt][nt] = __builtin_amdgcn_mfma_f32_16x16x32_bf16(
              af[mt], bfr[nt], acc[mt][nt], 0, 0, 0);
          if constexpr (MODE == 3)
            acc2[mt][nt] = __builtin_amdgcn_mfma_f32_16x16x32_bf16(
                af[mt], bfr2[nt], acc2[mt][nt], 0, 0, 0);
        }
    }
    __syncthreads();
  }

  // Epilogue. C/D layout: row = quad*4 + r (m), col = lane&15 (n).
  const int mbase = m0 + wm * 64 + quad * 4;
  const int nbase = n0 + wn * 32 + lr;
  #pragma unroll
  for (int mt = 0; mt < 4; mt++)
    #pragma unroll
    for (int nt = 0; nt < 2; nt++) {
      const int n = nbase + nt * 16;
      #pragma unroll
      for (int r = 0; r < 4; r++) {
        const int m = mbase + mt * 16 + r;
        const float v = acc[mt][nt][r];
        if constexpr (MODE == 0) {
          ((u16*)outp)[(size_t)m * N + n] = f2bf(v);
        } else if constexpr (MODE == 1) {
          ((float*)outp)[(size_t)m * N + n] = v + bias[n];
        } else if constexpr (MODE == 2) {
          float t = v + bf2f(xnp[(size_t)m * 1024 + n]) * ddiag[n];
          float g = t * 0.5f * (1.f + erff(t * 0.70710678118f));
          ((u16*)outp)[(size_t)m * N + n] = f2bf(g);
        } else {
          float a = v + bias[n];
          float g2 = acc2[mt][nt][r] + bias2[n];
          float sig = 1.f / (1.f + expf(-g2));
          float* xp = (float*)outp;
          xp[(size_t)m * N + n] += a * sig;
        }
      }
    }
}

extern "C" void kernel_launch(void* const* d_in, const int* in_sizes, int n_in,
                              void* d_out, int out_size, void* d_ws,
                              size_t ws_size, hipStream_t stream) {
  const float* inputs    = (const float*)d_in[0];
  const float* W_in      = (const float*)d_in[1];
  const float* b_in      = (const float*)d_in[2];
  const float* nu_log    = (const float*)d_in[3];
  const float* theta_log = (const float*)d_in[4];
  const float* B_re      = (const float*)d_in[5];
  const float* B_im      = (const float*)d_in[6];
  const float* C_re      = (const float*)d_in[7];
  const float* C_im      = (const float*)d_in[8];
  const float* D_diag    = (const float*)d_in[9];
  const float* ln_s      = (const float*)d_in[10];
  const float* ln_b      = (const float*)d_in[11];
  const float* w1        = (const float*)d_in[12];
  const float* b1        = (const float*)d_in[13];
  const float* w2        = (const float*)d_in[14];
  const float* b2        = (const float*)d_in[15];
  float* x = (float*)d_out;

  char* p = (char*)d_ws;
  auto alloc = [&](size_t bytes) -> char* {
    char* r = p;
    p += (bytes + 255) & ~(size_t)255;
    return r;
  };
  float* P       = (float*)alloc(5 * PLANE * 4);
  u16* inputs_bf = (u16*)alloc((size_t)MM * FF * 2);
  u16* Win_bf    = (u16*)alloc((size_t)DD * FF * 2);
  u16* xn        = (u16*)alloc((size_t)MM * DD * 2);
  u16* Bu        = (u16*)alloc((size_t)MM * 2048 * 2);
  u16* yg        = (u16*)alloc((size_t)MM * DD * 2);
  float* st      = (float*)alloc(2 * (size_t)STPLANE * 4);
  u16* wBn       = (u16*)alloc((size_t)2048 * 1024 * 2);
  u16* wC        = (u16*)alloc((size_t)1024 * 2048 * 2);
  u16* w1b       = (u16*)alloc((size_t)1024 * 1024 * 2);
  u16* w2b       = (u16*)alloc((size_t)1024 * 1024 * 2);

  params_kernel<<<16, 256, 0, stream>>>(nu_log, theta_log, P);
  f2bf_kernel<<<(MM * FF + 255) / 256, 256, 0, stream>>>(inputs, inputs_bf, MM * FF);
  f2bf_kernel<<<(DD * FF + 255) / 256, 256, 0, stream>>>(W_in, Win_bf, DD * FF);

  // x = inputs @ W_in^T + b_in
  gemm_kernel<1><<<dim3(64, 16), 256, 0, stream>>>(
      inputs_bf, Win_bf, nullptr, FF, DD, x, b_in, nullptr, nullptr, nullptr);

  for (int l = 0; l < NLAYER; l++) {
    ln_kernel<<<MM, 256, 0, stream>>>(x, ln_s + l * 1024, ln_b + l * 1024, xn);
    conv_layer_kernel<<<24576, 256, 0, stream>>>(
        B_re + (size_t)l * 1048576, B_im + (size_t)l * 1048576,
        C_re + (size_t)l * 1048576, C_im + (size_t)l * 1048576,
        w1 + (size_t)l * 1048576, w2 + (size_t)l * 1048576,
        P + 2 * PLANE + l * 1024, wBn, wC, w1b, w2b);
    // Bu = xn @ [gamma*B_re ; gamma*B_im]^T   (N = 2048)
    gemm_kernel<0><<<dim3(64, 32), 256, 0, stream>>>(
        xn, wBn, nullptr, DD, 2048, Bu, nullptr, nullptr, nullptr, nullptr);
    scanA_kernel<<<256, 256, 0, stream>>>(Bu, P, st, l);
    scanB_kernel<<<16, 256, 0, stream>>>(st, P, l);
    scanC_kernel<<<256, 256, 0, stream>>>(Bu, P, st, l);
    // yg = gelu( [hs_re|hs_im] @ [C_re ; -C_im]^T + xn*D_diag )   (K = 2048)
    gemm_kernel<2><<<dim3(64, 16), 256, 0, stream>>>(
        Bu, wC, nullptr, 2048, DD, yg, nullptr, nullptr, D_diag + l * 1024, xn);
    // x += (yg@w1^T + b1) * sigmoid(yg@w2^T + b2)
    gemm_kernel<3><<<dim3(64, 16), 256, 0, stream>>>(
        yg, w1b, w2b, DD, DD, x, b1 + l * 1024, b2 + l * 1024, nullptr, nullptr);
  }
}